// Round 9
// baseline (79.448 us; speedup 1.0000x reference)
//
#include <hip/hip_runtime.h>
#include <math.h>

namespace {

constexpr int Bsz = 64;
constexpr int Nn  = 1024;
constexpr int Dd  = 512;
constexpr int NCH = 32;            // colsum chunks per batch (32 rows each)
constexpr int CRW = Nn / NCH;      // 32 rows per colsum block
constexpr int SCH = 32;            // fused chunks per batch (32 rows each)
constexpr int SRW = Nn / SCH;      // 32 rows per fused block
constexpr int GCH = 8;             // e-slices for prep (64 rows each)
constexpr float SCALE = 0.044194173824159216f;  // 1/sqrt(512)

// Pass 1: partial column sums of x. grid(NCH, B) = 2048 blocks, block 256,
// 8 blocks/CU (32 waves/CU) for max memory-level parallelism.
__global__ __launch_bounds__(256, 8) void k_colsum(const float* __restrict__ x,
                                                   float* __restrict__ part) {
  const int i = blockIdx.x, b = blockIdx.y, t = threadIdx.x;
  const int cg = t & 127;          // column group (4 floats)
  const int p  = t >> 7;           // row parity
  const float* xb = x + ((size_t)b * Nn + (size_t)i * CRW + p) * Dd + cg * 4;
  float4 a0 = make_float4(0.f, 0.f, 0.f, 0.f);
  float4 a1 = make_float4(0.f, 0.f, 0.f, 0.f);
  #pragma unroll
  for (int j = 0; j < 16; j += 2) {
    const float4 v0 = *reinterpret_cast<const float4*>(xb + (size_t)(2 * j) * Dd);
    const float4 v1 = *reinterpret_cast<const float4*>(xb + (size_t)(2 * j + 2) * Dd);
    a0.x += v0.x; a0.y += v0.y; a0.z += v0.z; a0.w += v0.w;
    a1.x += v1.x; a1.y += v1.y; a1.z += v1.z; a1.w += v1.w;
  }
  a0.x += a1.x; a0.y += a1.y; a0.z += a1.z; a0.w += a1.w;

  __shared__ __align__(16) float red[2][Dd];
  *reinterpret_cast<float4*>(&red[p][cg * 4]) = a0;
  __syncthreads();
  if (t < 128) {
    const float4 r0 = *reinterpret_cast<const float4*>(&red[0][t * 4]);
    const float4 r1 = *reinterpret_cast<const float4*>(&red[1][t * 4]);
    float4 o;
    o.x = r0.x + r1.x; o.y = r0.y + r1.y; o.z = r0.z + r1.z; o.w = r0.w + r1.w;
    *reinterpret_cast<float4*>(part + (size_t)(b * NCH + i) * Dd + t * 4) = o;
  }
}

// Pass 2 (merged prep): block (g,b): wave-split part->xbar, kbar slice via
// wave-per-row dots, then u-partial: upart[b][g][d] = sum_{e in slice} kbar_e*Wq[e][d].
// grid(GCH, B), block 256 (4 waves). (c = bq.kbar dropped: softmax shift-inv.)
__global__ __launch_bounds__(256) void k_prep2(const float* __restrict__ part,
                                               const float* __restrict__ Wq,
                                               const float* __restrict__ Wk,
                                               const float* __restrict__ bk,
                                               float* __restrict__ upart) {
  const int g = blockIdx.x, b = blockIdx.y, t = threadIdx.x;
  const int wave = t >> 6, lane = t & 63;
  __shared__ __align__(16) float xbar[Dd];
  __shared__ __align__(16) float wred[4][Dd];
  __shared__ float kb[64];

  // wave-split xbar reduce: wave w sums partials [w*8, w*8+8), lane covers 8 cols
  {
    float4 a0 = make_float4(0.f, 0.f, 0.f, 0.f);
    float4 a1 = make_float4(0.f, 0.f, 0.f, 0.f);
    const float* pb = part + ((size_t)b * NCH + wave * 8) * Dd + lane * 8;
    #pragma unroll
    for (int ch = 0; ch < 8; ++ch) {
      const float4 v0 = *reinterpret_cast<const float4*>(pb + (size_t)ch * Dd);
      const float4 v1 = *reinterpret_cast<const float4*>(pb + (size_t)ch * Dd + 4);
      a0.x += v0.x; a0.y += v0.y; a0.z += v0.z; a0.w += v0.w;
      a1.x += v1.x; a1.y += v1.y; a1.z += v1.z; a1.w += v1.w;
    }
    *reinterpret_cast<float4*>(&wred[wave][lane * 8])     = a0;
    *reinterpret_cast<float4*>(&wred[wave][lane * 8 + 4]) = a1;
  }
  __syncthreads();
  xbar[t]       = (wred[0][t]       + wred[1][t]       + wred[2][t]       + wred[3][t])       * (1.0f / Nn);
  xbar[t + 256] = (wred[0][t + 256] + wred[1][t + 256] + wred[2][t + 256] + wred[3][t + 256]) * (1.0f / Nn);
  __syncthreads();

  const float4 xv1 = *reinterpret_cast<const float4*>(xbar + lane * 4);
  const float4 xv2 = *reinterpret_cast<const float4*>(xbar + 256 + lane * 4);

  // wave handles slice rows [wave*16, wave*16+16), 2 in flight
  for (int i = 0; i < 16; i += 2) {
    const int l0 = wave * 16 + i, l1 = l0 + 1;
    const int e0 = g * 64 + l0, e1 = e0 + 1;
    const float4* r0 = reinterpret_cast<const float4*>(Wk + (size_t)e0 * Dd);
    const float4* r1 = reinterpret_cast<const float4*>(Wk + (size_t)e1 * Dd);
    const float4 a0 = r0[lane], b0 = r0[64 + lane];
    const float4 a1 = r1[lane], b1 = r1[64 + lane];
    float d0 = a0.x*xv1.x + a0.y*xv1.y + a0.z*xv1.z + a0.w*xv1.w
             + b0.x*xv2.x + b0.y*xv2.y + b0.z*xv2.z + b0.w*xv2.w;
    float d1 = a1.x*xv1.x + a1.y*xv1.y + a1.z*xv1.z + a1.w*xv1.w
             + b1.x*xv2.x + b1.y*xv2.y + b1.z*xv2.z + b1.w*xv2.w;
    #pragma unroll
    for (int off = 32; off > 0; off >>= 1) {
      d0 += __shfl_xor(d0, off);
      d1 += __shfl_xor(d1, off);
    }
    if (lane == 0) { kb[l0] = bk[e0] + d0; kb[l1] = bk[e1] + d1; }
  }
  __syncthreads();

  // u-partial for this slice: thread t covers d = t and d = t+256.
  const float* Wbase = Wq + (size_t)(g * 64) * Dd;
  float a0 = 0.f, a1 = 0.f, a2 = 0.f, a3 = 0.f;
  #pragma unroll 8
  for (int e = 0; e < 64; e += 2) {
    const float k0 = kb[e], k1 = kb[e + 1];
    a0 += k0 * Wbase[(size_t)e * Dd + t];
    a1 += k0 * Wbase[(size_t)e * Dd + t + 256];
    a2 += k1 * Wbase[(size_t)(e + 1) * Dd + t];
    a3 += k1 * Wbase[(size_t)(e + 1) * Dd + t + 256];
  }
  float* ub = upart + (size_t)(b * GCH + g) * Dd;
  ub[t]       = a0 + a2;
  ub[t + 256] = a1 + a3;
}

// Pass 3 (fused, branch-free): s[b,n] = x_n.u_b * SCALE; accumulate exp(s_n)*x_n.
// grid(SCH, B) = 2048 blocks, block 256 (4 waves, 8 rows each, 2 in flight),
// 6 blocks/CU (24 waves/CU).
__global__ __launch_bounds__(256, 6) void k_fused(const float* __restrict__ x,
                                                  const float* __restrict__ upart,
                                                  float* __restrict__ s,
                                                  float* __restrict__ P) {
  const int ch = blockIdx.x, b = blockIdx.y, t = threadIdx.x;
  const int wave = t >> 6, lane = t & 63;

  // u = sum of GCH partials (tiny L2 reads)
  float4 u1 = make_float4(0.f, 0.f, 0.f, 0.f);
  float4 u2 = make_float4(0.f, 0.f, 0.f, 0.f);
  #pragma unroll
  for (int h = 0; h < GCH; ++h) {
    const float* ub = upart + (size_t)(b * GCH + h) * Dd;
    const float4 p1 = *reinterpret_cast<const float4*>(ub + lane * 4);
    const float4 p2 = *reinterpret_cast<const float4*>(ub + 256 + lane * 4);
    u1.x += p1.x; u1.y += p1.y; u1.z += p1.z; u1.w += p1.w;
    u2.x += p2.x; u2.y += p2.y; u2.z += p2.z; u2.w += p2.w;
  }

  const float* xb = x + ((size_t)b * Nn + (size_t)ch * SRW) * Dd;
  float* sb = s + (size_t)b * Nn + (size_t)ch * SRW;

  float4 a1 = make_float4(0.f, 0.f, 0.f, 0.f);
  float4 a2 = make_float4(0.f, 0.f, 0.f, 0.f);

  #pragma unroll
  for (int i = 0; i < 8; i += 2) {
    const int r0 = wave + 4 * i, r1 = wave + 4 * (i + 1);
    const float4* xr0 = reinterpret_cast<const float4*>(xb + (size_t)r0 * Dd);
    const float4* xr1 = reinterpret_cast<const float4*>(xb + (size_t)r1 * Dd);
    const float4 va0 = xr0[lane], vb0 = xr0[64 + lane];
    const float4 va1 = xr1[lane], vb1 = xr1[64 + lane];
    float d0 = va0.x*u1.x + va0.y*u1.y + va0.z*u1.z + va0.w*u1.w
             + vb0.x*u2.x + vb0.y*u2.y + vb0.z*u2.z + vb0.w*u2.w;
    float d1 = va1.x*u1.x + va1.y*u1.y + va1.z*u1.z + va1.w*u1.w
             + vb1.x*u2.x + vb1.y*u2.y + vb1.z*u2.z + vb1.w*u2.w;
    #pragma unroll
    for (int off = 32; off > 0; off >>= 1) {
      d0 += __shfl_xor(d0, off);
      d1 += __shfl_xor(d1, off);
    }
    const float s0 = d0 * SCALE, s1 = d1 * SCALE;
    if (lane == 0) { sb[r0] = s0; sb[r1] = s1; }
    const float e0 = __expf(s0), e1 = __expf(s1);
    a1.x += e0*va0.x + e1*va1.x; a1.y += e0*va0.y + e1*va1.y;
    a1.z += e0*va0.z + e1*va1.z; a1.w += e0*va0.w + e1*va1.w;
    a2.x += e0*vb0.x + e1*vb1.x; a2.y += e0*vb0.y + e1*vb1.y;
    a2.z += e0*vb0.z + e1*vb1.z; a2.w += e0*vb0.w + e1*vb1.w;
  }

  __shared__ __align__(16) float pacc[4][Dd];
  *reinterpret_cast<float4*>(&pacc[wave][lane * 4]) = a1;
  *reinterpret_cast<float4*>(&pacc[wave][256 + lane * 4]) = a2;
  __syncthreads();
  float* Pb = P + (size_t)(b * SCH + ch) * Dd;
  Pb[t]       = pacc[0][t]       + pacc[1][t]       + pacc[2][t]       + pacc[3][t];
  Pb[t + 256] = pacc[0][t + 256] + pacc[1][t + 256] + pacc[2][t + 256] + pacc[3][t + 256];
}

// Pass 4: w = exp(s)/Z (no max needed, |s| small); agg = (sum_ch P_ch)/Z.
// grid(B), 256 thr.
__global__ __launch_bounds__(256) void k_final(const float* __restrict__ s,
                                               const float* __restrict__ P,
                                               float* __restrict__ w,
                                               float* __restrict__ agg) {
  const int b = blockIdx.x, t = threadIdx.x;
  const int wave = t >> 6, lane = t & 63;
  __shared__ float lred[4];

  float e[4];
  float sum = 0.f;
  #pragma unroll
  for (int i = 0; i < 4; ++i) {
    e[i] = expf(s[(size_t)b * Nn + t + i * 256]);
    sum += e[i];
  }
  #pragma unroll
  for (int off = 32; off > 0; off >>= 1) sum += __shfl_xor(sum, off);
  if (lane == 0) lred[wave] = sum;
  __syncthreads();
  sum = lred[0] + lred[1] + lred[2] + lred[3];
  const float inv = 1.0f / sum;
  #pragma unroll
  for (int i = 0; i < 4; ++i) w[(size_t)b * Nn + t + i * 256] = e[i] * inv;

  float g0 = 0.f, g1 = 0.f;
  #pragma unroll 8
  for (int chh = 0; chh < SCH; ++chh) {
    g0 += P[(size_t)(b * SCH + chh) * Dd + t];
    g1 += P[(size_t)(b * SCH + chh) * Dd + t + 256];
  }
  agg[(size_t)b * Dd + t]       = g0 * inv;
  agg[(size_t)b * Dd + t + 256] = g1 * inv;
}

}  // namespace

extern "C" void kernel_launch(void* const* d_in, const int* in_sizes, int n_in,
                              void* d_out, int out_size, void* d_ws, size_t ws_size,
                              hipStream_t stream) {
  const float* x  = (const float*)d_in[0];
  const float* Wq = (const float*)d_in[1];
  const float* Wk = (const float*)d_in[3];
  const float* bk = (const float*)d_in[4];

  float* out = (float*)d_out;
  float* agg = out;                       // [B][D]
  float* w   = out + (size_t)Bsz * Dd;    // [B][N]

  // workspace (floats): part | upart | s | P   (~9.5 MiB, same as validated R4)
  float* part  = (float*)d_ws;                          // B*NCH*D = 1,048,576
  float* upart = part + (size_t)Bsz * NCH * Dd;         // B*GCH*D =   262,144
  float* s     = upart + (size_t)Bsz * GCH * Dd;        // B*N     =    65,536
  float* P     = s + (size_t)Bsz * Nn;                  // B*SCH*D = 1,048,576

  k_colsum<<<dim3(NCH, Bsz), 256, 0, stream>>>(x, part);
  k_prep2 <<<dim3(GCH, Bsz), 256, 0, stream>>>(part, Wq, Wk, bk, upart);
  k_fused <<<dim3(SCH, Bsz), 256, 0, stream>>>(x, upart, s, P);
  k_final <<<Bsz, 256, 0, stream>>>(s, P, w, agg);
}

// Round 10
// 70.583 us; speedup vs baseline: 1.1256x; 1.1256x over previous
//
#include <hip/hip_runtime.h>
#include <math.h>

namespace {

constexpr int Bsz = 64;
constexpr int Nn  = 1024;
constexpr int Dd  = 512;
constexpr int NCH = 32;            // colsum chunks per batch (32 rows each)
constexpr int PPB = NCH * 2;       // partials per batch (2 row-halves/chunk) = 64
constexpr int SCH = 16;            // fused chunks per batch (64 rows each)
constexpr int SRW = Nn / SCH;      // 64 rows per fused block
constexpr int GCH = 8;             // e-slices for prep (64 rows each)
constexpr float SCALE = 0.044194173824159216f;  // 1/sqrt(512)

// Pass 1: partial column sums of x. grid(NCH, B) = 2048 blocks, block 256.
// NO min-wave launch_bounds (VGPR cap would throttle in-flight loads — R9 lesson).
// Thread t: column-group cg (4 floats), row-half h; sums 16 contiguous-stride rows
// with 16 independent loads, 2 accumulators; writes its partial directly.
__global__ __launch_bounds__(256) void k_colsum(const float* __restrict__ x,
                                                float* __restrict__ part) {
  const int i = blockIdx.x, b = blockIdx.y, t = threadIdx.x;
  const int cg = t & 127;          // column group (4 floats)
  const int h  = t >> 7;           // row half (0: rows 0-15, 1: rows 16-31)
  const float* xb = x + ((size_t)b * Nn + (size_t)i * 32 + h * 16) * Dd + cg * 4;
  float4 a0 = make_float4(0.f, 0.f, 0.f, 0.f);
  float4 a1 = make_float4(0.f, 0.f, 0.f, 0.f);
  #pragma unroll
  for (int j = 0; j < 16; j += 2) {
    const float4 v0 = *reinterpret_cast<const float4*>(xb + (size_t)j * Dd);
    const float4 v1 = *reinterpret_cast<const float4*>(xb + (size_t)(j + 1) * Dd);
    a0.x += v0.x; a0.y += v0.y; a0.z += v0.z; a0.w += v0.w;
    a1.x += v1.x; a1.y += v1.y; a1.z += v1.z; a1.w += v1.w;
  }
  a0.x += a1.x; a0.y += a1.y; a0.z += a1.z; a0.w += a1.w;
  *reinterpret_cast<float4*>(part + (size_t)(b * PPB + i * 2 + h) * Dd + cg * 4) = a0;
}

// Pass 2 (merged prep): block (g,b): wave-split part->xbar, kbar slice via
// wave-per-row dots, then u-partial: upart[b][g][d] = sum_{e in slice} kbar_e*Wq[e][d].
// grid(GCH, B), block 256 (4 waves). (c = bq.kbar dropped: softmax shift-inv.)
__global__ __launch_bounds__(256) void k_prep2(const float* __restrict__ part,
                                               const float* __restrict__ Wq,
                                               const float* __restrict__ Wk,
                                               const float* __restrict__ bk,
                                               float* __restrict__ upart) {
  const int g = blockIdx.x, b = blockIdx.y, t = threadIdx.x;
  const int wave = t >> 6, lane = t & 63;
  __shared__ __align__(16) float xbar[Dd];
  __shared__ __align__(16) float wred[4][Dd];
  __shared__ float kb[64];

  // wave-split xbar reduce: wave w sums partials [w*16, w*16+16), lane covers 8 cols
  {
    float4 a0 = make_float4(0.f, 0.f, 0.f, 0.f);
    float4 a1 = make_float4(0.f, 0.f, 0.f, 0.f);
    const float* pb = part + ((size_t)b * PPB + wave * 16) * Dd + lane * 8;
    #pragma unroll
    for (int ch = 0; ch < 16; ++ch) {
      const float4 v0 = *reinterpret_cast<const float4*>(pb + (size_t)ch * Dd);
      const float4 v1 = *reinterpret_cast<const float4*>(pb + (size_t)ch * Dd + 4);
      a0.x += v0.x; a0.y += v0.y; a0.z += v0.z; a0.w += v0.w;
      a1.x += v1.x; a1.y += v1.y; a1.z += v1.z; a1.w += v1.w;
    }
    *reinterpret_cast<float4*>(&wred[wave][lane * 8])     = a0;
    *reinterpret_cast<float4*>(&wred[wave][lane * 8 + 4]) = a1;
  }
  __syncthreads();
  xbar[t]       = (wred[0][t]       + wred[1][t]       + wred[2][t]       + wred[3][t])       * (1.0f / Nn);
  xbar[t + 256] = (wred[0][t + 256] + wred[1][t + 256] + wred[2][t + 256] + wred[3][t + 256]) * (1.0f / Nn);
  __syncthreads();

  const float4 xv1 = *reinterpret_cast<const float4*>(xbar + lane * 4);
  const float4 xv2 = *reinterpret_cast<const float4*>(xbar + 256 + lane * 4);

  // wave handles slice rows [wave*16, wave*16+16), 2 in flight
  for (int i = 0; i < 16; i += 2) {
    const int l0 = wave * 16 + i, l1 = l0 + 1;
    const int e0 = g * 64 + l0, e1 = e0 + 1;
    const float4* r0 = reinterpret_cast<const float4*>(Wk + (size_t)e0 * Dd);
    const float4* r1 = reinterpret_cast<const float4*>(Wk + (size_t)e1 * Dd);
    const float4 a0 = r0[lane], b0 = r0[64 + lane];
    const float4 a1 = r1[lane], b1 = r1[64 + lane];
    float d0 = a0.x*xv1.x + a0.y*xv1.y + a0.z*xv1.z + a0.w*xv1.w
             + b0.x*xv2.x + b0.y*xv2.y + b0.z*xv2.z + b0.w*xv2.w;
    float d1 = a1.x*xv1.x + a1.y*xv1.y + a1.z*xv1.z + a1.w*xv1.w
             + b1.x*xv2.x + b1.y*xv2.y + b1.z*xv2.z + b1.w*xv2.w;
    #pragma unroll
    for (int off = 32; off > 0; off >>= 1) {
      d0 += __shfl_xor(d0, off);
      d1 += __shfl_xor(d1, off);
    }
    if (lane == 0) { kb[l0] = bk[e0] + d0; kb[l1] = bk[e1] + d1; }
  }
  __syncthreads();

  // u-partial for this slice: thread t covers d = t and d = t+256.
  const float* Wbase = Wq + (size_t)(g * 64) * Dd;
  float a0 = 0.f, a1 = 0.f, a2 = 0.f, a3 = 0.f;
  #pragma unroll 8
  for (int e = 0; e < 64; e += 2) {
    const float k0 = kb[e], k1 = kb[e + 1];
    a0 += k0 * Wbase[(size_t)e * Dd + t];
    a1 += k0 * Wbase[(size_t)e * Dd + t + 256];
    a2 += k1 * Wbase[(size_t)(e + 1) * Dd + t];
    a3 += k1 * Wbase[(size_t)(e + 1) * Dd + t + 256];
  }
  float* ub = upart + (size_t)(b * GCH + g) * Dd;
  ub[t]       = a0 + a2;
  ub[t + 256] = a1 + a3;
}

// Pass 3 (fused, branch-free): s[b,n] = x_n.u_b * SCALE; accumulate exp(s_n)*x_n.
// grid(SCH, B), block 256 (4 waves, 16 rows each, 2 in flight). 128 KB stream/block.
// Identical to the validated R8 62.1 us version.
__global__ __launch_bounds__(256) void k_fused(const float* __restrict__ x,
                                               const float* __restrict__ upart,
                                               float* __restrict__ s,
                                               float* __restrict__ P) {
  const int ch = blockIdx.x, b = blockIdx.y, t = threadIdx.x;
  const int wave = t >> 6, lane = t & 63;

  // u = sum of GCH partials (tiny L2 reads)
  float4 u1 = make_float4(0.f, 0.f, 0.f, 0.f);
  float4 u2 = make_float4(0.f, 0.f, 0.f, 0.f);
  #pragma unroll
  for (int h = 0; h < GCH; ++h) {
    const float* ub = upart + (size_t)(b * GCH + h) * Dd;
    const float4 p1 = *reinterpret_cast<const float4*>(ub + lane * 4);
    const float4 p2 = *reinterpret_cast<const float4*>(ub + 256 + lane * 4);
    u1.x += p1.x; u1.y += p1.y; u1.z += p1.z; u1.w += p1.w;
    u2.x += p2.x; u2.y += p2.y; u2.z += p2.z; u2.w += p2.w;
  }

  const float* xb = x + ((size_t)b * Nn + (size_t)ch * SRW) * Dd;
  float* sb = s + (size_t)b * Nn + (size_t)ch * SRW;

  float4 a1 = make_float4(0.f, 0.f, 0.f, 0.f);
  float4 a2 = make_float4(0.f, 0.f, 0.f, 0.f);

  #pragma unroll 2
  for (int i = 0; i < 16; i += 2) {
    const int r0 = wave + 4 * i, r1 = wave + 4 * (i + 1);
    const float4* xr0 = reinterpret_cast<const float4*>(xb + (size_t)r0 * Dd);
    const float4* xr1 = reinterpret_cast<const float4*>(xb + (size_t)r1 * Dd);
    const float4 va0 = xr0[lane], vb0 = xr0[64 + lane];
    const float4 va1 = xr1[lane], vb1 = xr1[64 + lane];
    float d0 = va0.x*u1.x + va0.y*u1.y + va0.z*u1.z + va0.w*u1.w
             + vb0.x*u2.x + vb0.y*u2.y + vb0.z*u2.z + vb0.w*u2.w;
    float d1 = va1.x*u1.x + va1.y*u1.y + va1.z*u1.z + va1.w*u1.w
             + vb1.x*u2.x + vb1.y*u2.y + vb1.z*u2.z + vb1.w*u2.w;
    #pragma unroll
    for (int off = 32; off > 0; off >>= 1) {
      d0 += __shfl_xor(d0, off);
      d1 += __shfl_xor(d1, off);
    }
    const float s0 = d0 * SCALE, s1 = d1 * SCALE;
    if (lane == 0) { sb[r0] = s0; sb[r1] = s1; }
    const float e0 = __expf(s0), e1 = __expf(s1);
    a1.x += e0*va0.x + e1*va1.x; a1.y += e0*va0.y + e1*va1.y;
    a1.z += e0*va0.z + e1*va1.z; a1.w += e0*va0.w + e1*va1.w;
    a2.x += e0*vb0.x + e1*vb1.x; a2.y += e0*vb0.y + e1*vb1.y;
    a2.z += e0*vb0.z + e1*vb1.z; a2.w += e0*vb0.w + e1*vb1.w;
  }

  __shared__ __align__(16) float pacc[4][Dd];
  *reinterpret_cast<float4*>(&pacc[wave][lane * 4]) = a1;
  *reinterpret_cast<float4*>(&pacc[wave][256 + lane * 4]) = a2;
  __syncthreads();
  float* Pb = P + (size_t)(b * SCH + ch) * Dd;
  Pb[t]       = pacc[0][t]       + pacc[1][t]       + pacc[2][t]       + pacc[3][t];
  Pb[t + 256] = pacc[0][t + 256] + pacc[1][t + 256] + pacc[2][t + 256] + pacc[3][t + 256];
}

// Pass 4: w = exp(s)/Z (no max needed, |s| small); agg = (sum_ch P_ch)/Z.
// grid(B), 256 thr. Identical to R8.
__global__ __launch_bounds__(256) void k_final(const float* __restrict__ s,
                                               const float* __restrict__ P,
                                               float* __restrict__ w,
                                               float* __restrict__ agg) {
  const int b = blockIdx.x, t = threadIdx.x;
  const int wave = t >> 6, lane = t & 63;
  __shared__ float lred[4];

  float e[4];
  float sum = 0.f;
  #pragma unroll
  for (int i = 0; i < 4; ++i) {
    e[i] = expf(s[(size_t)b * Nn + t + i * 256]);
    sum += e[i];
  }
  #pragma unroll
  for (int off = 32; off > 0; off >>= 1) sum += __shfl_xor(sum, off);
  if (lane == 0) lred[wave] = sum;
  __syncthreads();
  sum = lred[0] + lred[1] + lred[2] + lred[3];
  const float inv = 1.0f / sum;
  #pragma unroll
  for (int i = 0; i < 4; ++i) w[(size_t)b * Nn + t + i * 256] = e[i] * inv;

  float g0 = 0.f, g1 = 0.f;
  #pragma unroll 8
  for (int chh = 0; chh < SCH; ++chh) {
    g0 += P[(size_t)(b * SCH + chh) * Dd + t];
    g1 += P[(size_t)(b * SCH + chh) * Dd + t + 256];
  }
  agg[(size_t)b * Dd + t]       = g0 * inv;
  agg[(size_t)b * Dd + t + 256] = g1 * inv;
}

}  // namespace

extern "C" void kernel_launch(void* const* d_in, const int* in_sizes, int n_in,
                              void* d_out, int out_size, void* d_ws, size_t ws_size,
                              hipStream_t stream) {
  const float* x  = (const float*)d_in[0];
  const float* Wq = (const float*)d_in[1];
  const float* Wk = (const float*)d_in[3];
  const float* bk = (const float*)d_in[4];

  float* out = (float*)d_out;
  float* agg = out;                       // [B][D]
  float* w   = out + (size_t)Bsz * Dd;    // [B][N]

  // workspace (floats): part | upart | s | P   (~11.8 MiB)
  float* part  = (float*)d_ws;                          // B*PPB*D = 2,097,152
  float* upart = part + (size_t)Bsz * PPB * Dd;         // B*GCH*D =   262,144
  float* s     = upart + (size_t)Bsz * GCH * Dd;        // B*N     =    65,536
  float* P     = s + (size_t)Bsz * Nn;                  // B*SCH*D =   524,288

  k_colsum<<<dim3(NCH, Bsz), 256, 0, stream>>>(x, part);
  k_prep2 <<<dim3(GCH, Bsz), 256, 0, stream>>>(part, Wq, Wk, bk, upart);
  k_fused <<<dim3(SCH, Bsz), 256, 0, stream>>>(x, upart, s, P);
  k_final <<<Bsz, 256, 0, stream>>>(s, P, w, agg);
}

// Round 11
// 62.185 us; speedup vs baseline: 1.2776x; 1.1350x over previous
//
#include <hip/hip_runtime.h>
#include <math.h>

namespace {

constexpr int Bsz = 64;
constexpr int Nn  = 1024;
constexpr int Dd  = 512;
constexpr int NCH = 8;             // n-chunks for column-sum pass (128 rows each)
constexpr int PPB = NCH * 2;       // partials per batch (2 parities per chunk) = 16
constexpr int SCH = 16;            // n-chunks for fused pass (64 rows each)
constexpr int SRW = Nn / SCH;      // 64 rows per fused block
constexpr int GCH = 8;             // e-slices for prep (64 rows each)
constexpr int FB  = 4;             // final blocks per batch
constexpr float SCALE = 0.044194173824159216f;  // 1/sqrt(512)

// Pass 1: partial column sums of x. grid(NCH, B) = 512 blocks, block 256 (8 waves).
// Block (i,b) streams rows [i*128, i*128+128) contiguously (256 KB). [R8-proven]
__global__ __launch_bounds__(256) void k_colsum(const float* __restrict__ x,
                                                float* __restrict__ part) {
  const int i = blockIdx.x, b = blockIdx.y, t = threadIdx.x;
  const int col = (t & 127) * 4;   // 4 columns per thread
  const int p = t >> 7;            // row parity
  const float* xb = x + ((size_t)b * Nn + (size_t)i * 128) * Dd;
  float4 acc = make_float4(0.f, 0.f, 0.f, 0.f);
  #pragma unroll 8
  for (int j = 0; j < 64; ++j) {
    const int n = j * 2 + p;
    const float4 v = *reinterpret_cast<const float4*>(xb + (size_t)n * Dd + col);
    acc.x += v.x; acc.y += v.y; acc.z += v.z; acc.w += v.w;
  }
  *reinterpret_cast<float4*>(part + ((size_t)(b * NCH + i) * 2 + p) * Dd + col) = acc;
}

// Pass 2 (merged prep): block (g,b): wave-split part->xbar, kbar slice via
// wave-per-row dots, then u-partial: upart[b][g][d] = sum_{e in slice} kbar_e*Wq[e][d].
// grid(GCH, B), block 256 (4 waves). (c = bq.kbar dropped: softmax shift-inv.) [R8-proven]
__global__ __launch_bounds__(256) void k_prep2(const float* __restrict__ part,
                                               const float* __restrict__ Wq,
                                               const float* __restrict__ Wk,
                                               const float* __restrict__ bk,
                                               float* __restrict__ upart) {
  const int g = blockIdx.x, b = blockIdx.y, t = threadIdx.x;
  const int wave = t >> 6, lane = t & 63;
  __shared__ __align__(16) float xbar[Dd];
  __shared__ __align__(16) float wred[4][Dd];
  __shared__ float kb[64];

  // wave-split xbar reduce: wave w sums partials [w*4, w*4+4), lane covers 8 cols
  {
    float4 a0 = make_float4(0.f, 0.f, 0.f, 0.f);
    float4 a1 = make_float4(0.f, 0.f, 0.f, 0.f);
    const float* pb = part + ((size_t)b * PPB + wave * 4) * Dd + lane * 8;
    #pragma unroll
    for (int ch = 0; ch < 4; ++ch) {
      const float4 v0 = *reinterpret_cast<const float4*>(pb + (size_t)ch * Dd);
      const float4 v1 = *reinterpret_cast<const float4*>(pb + (size_t)ch * Dd + 4);
      a0.x += v0.x; a0.y += v0.y; a0.z += v0.z; a0.w += v0.w;
      a1.x += v1.x; a1.y += v1.y; a1.z += v1.z; a1.w += v1.w;
    }
    *reinterpret_cast<float4*>(&wred[wave][lane * 8])     = a0;
    *reinterpret_cast<float4*>(&wred[wave][lane * 8 + 4]) = a1;
  }
  __syncthreads();
  xbar[t]       = (wred[0][t]       + wred[1][t]       + wred[2][t]       + wred[3][t])       * (1.0f / Nn);
  xbar[t + 256] = (wred[0][t + 256] + wred[1][t + 256] + wred[2][t + 256] + wred[3][t + 256]) * (1.0f / Nn);
  __syncthreads();

  const float4 xv1 = *reinterpret_cast<const float4*>(xbar + lane * 4);
  const float4 xv2 = *reinterpret_cast<const float4*>(xbar + 256 + lane * 4);

  // wave handles slice rows [wave*16, wave*16+16), 2 in flight
  for (int i = 0; i < 16; i += 2) {
    const int l0 = wave * 16 + i, l1 = l0 + 1;
    const int e0 = g * 64 + l0, e1 = e0 + 1;
    const float4* r0 = reinterpret_cast<const float4*>(Wk + (size_t)e0 * Dd);
    const float4* r1 = reinterpret_cast<const float4*>(Wk + (size_t)e1 * Dd);
    const float4 a0 = r0[lane], b0 = r0[64 + lane];
    const float4 a1 = r1[lane], b1 = r1[64 + lane];
    float d0 = a0.x*xv1.x + a0.y*xv1.y + a0.z*xv1.z + a0.w*xv1.w
             + b0.x*xv2.x + b0.y*xv2.y + b0.z*xv2.z + b0.w*xv2.w;
    float d1 = a1.x*xv1.x + a1.y*xv1.y + a1.z*xv1.z + a1.w*xv1.w
             + b1.x*xv2.x + b1.y*xv2.y + b1.z*xv2.z + b1.w*xv2.w;
    #pragma unroll
    for (int off = 32; off > 0; off >>= 1) {
      d0 += __shfl_xor(d0, off);
      d1 += __shfl_xor(d1, off);
    }
    if (lane == 0) { kb[l0] = bk[e0] + d0; kb[l1] = bk[e1] + d1; }
  }
  __syncthreads();

  // u-partial for this slice: thread t covers d = t and d = t+256.
  const float* Wbase = Wq + (size_t)(g * 64) * Dd;
  float a0 = 0.f, a1 = 0.f, a2 = 0.f, a3 = 0.f;
  #pragma unroll 8
  for (int e = 0; e < 64; e += 2) {
    const float k0 = kb[e], k1 = kb[e + 1];
    a0 += k0 * Wbase[(size_t)e * Dd + t];
    a1 += k0 * Wbase[(size_t)e * Dd + t + 256];
    a2 += k1 * Wbase[(size_t)(e + 1) * Dd + t];
    a3 += k1 * Wbase[(size_t)(e + 1) * Dd + t + 256];
  }
  float* ub = upart + (size_t)(b * GCH + g) * Dd;
  ub[t]       = a0 + a2;
  ub[t + 256] = a1 + a3;
}

// Pass 3 (fused, branch-free): s[b,n] = x_n.u_b * SCALE; accumulate exp(s_n)*x_n.
// grid(SCH, B), block 256 (4 waves, 16 rows each, 2 in flight). 128 KB stream/block.
// [R8-proven]
__global__ __launch_bounds__(256) void k_fused(const float* __restrict__ x,
                                               const float* __restrict__ upart,
                                               float* __restrict__ s,
                                               float* __restrict__ P) {
  const int ch = blockIdx.x, b = blockIdx.y, t = threadIdx.x;
  const int wave = t >> 6, lane = t & 63;

  // u = sum of GCH partials (tiny L2 reads)
  float4 u1 = make_float4(0.f, 0.f, 0.f, 0.f);
  float4 u2 = make_float4(0.f, 0.f, 0.f, 0.f);
  #pragma unroll
  for (int h = 0; h < GCH; ++h) {
    const float* ub = upart + (size_t)(b * GCH + h) * Dd;
    const float4 p1 = *reinterpret_cast<const float4*>(ub + lane * 4);
    const float4 p2 = *reinterpret_cast<const float4*>(ub + 256 + lane * 4);
    u1.x += p1.x; u1.y += p1.y; u1.z += p1.z; u1.w += p1.w;
    u2.x += p2.x; u2.y += p2.y; u2.z += p2.z; u2.w += p2.w;
  }

  const float* xb = x + ((size_t)b * Nn + (size_t)ch * SRW) * Dd;
  float* sb = s + (size_t)b * Nn + (size_t)ch * SRW;

  float4 a1 = make_float4(0.f, 0.f, 0.f, 0.f);
  float4 a2 = make_float4(0.f, 0.f, 0.f, 0.f);

  #pragma unroll 2
  for (int i = 0; i < 16; i += 2) {
    const int r0 = wave + 4 * i, r1 = wave + 4 * (i + 1);
    const float4* xr0 = reinterpret_cast<const float4*>(xb + (size_t)r0 * Dd);
    const float4* xr1 = reinterpret_cast<const float4*>(xb + (size_t)r1 * Dd);
    const float4 va0 = xr0[lane], vb0 = xr0[64 + lane];
    const float4 va1 = xr1[lane], vb1 = xr1[64 + lane];
    float d0 = va0.x*u1.x + va0.y*u1.y + va0.z*u1.z + va0.w*u1.w
             + vb0.x*u2.x + vb0.y*u2.y + vb0.z*u2.z + vb0.w*u2.w;
    float d1 = va1.x*u1.x + va1.y*u1.y + va1.z*u1.z + va1.w*u1.w
             + vb1.x*u2.x + vb1.y*u2.y + vb1.z*u2.z + vb1.w*u2.w;
    #pragma unroll
    for (int off = 32; off > 0; off >>= 1) {
      d0 += __shfl_xor(d0, off);
      d1 += __shfl_xor(d1, off);
    }
    const float s0 = d0 * SCALE, s1 = d1 * SCALE;
    if (lane == 0) { sb[r0] = s0; sb[r1] = s1; }
    const float e0 = __expf(s0), e1 = __expf(s1);
    a1.x += e0*va0.x + e1*va1.x; a1.y += e0*va0.y + e1*va1.y;
    a1.z += e0*va0.z + e1*va1.z; a1.w += e0*va0.w + e1*va1.w;
    a2.x += e0*vb0.x + e1*vb1.x; a2.y += e0*vb0.y + e1*vb1.y;
    a2.z += e0*vb0.z + e1*vb1.z; a2.w += e0*vb0.w + e1*vb1.w;
  }

  __shared__ __align__(16) float pacc[4][Dd];
  *reinterpret_cast<float4*>(&pacc[wave][lane * 4]) = a1;
  *reinterpret_cast<float4*>(&pacc[wave][256 + lane * 4]) = a2;
  __syncthreads();
  float* Pb = P + (size_t)(b * SCH + ch) * Dd;
  Pb[t]       = pacc[0][t]       + pacc[1][t]       + pacc[2][t]       + pacc[3][t];
  Pb[t + 256] = pacc[0][t + 256] + pacc[1][t + 256] + pacc[2][t + 256] + pacc[3][t + 256];
}

// Pass 4 (widened): grid(FB, B) = 256 blocks. Each block redundantly computes
// Z[b] from s[b] (4 KB, L2), writes its quarter of w and its 128-column slice
// of agg. No max subtraction (|s| small; accumulators used unshifted exp).
__global__ __launch_bounds__(256) void k_final(const float* __restrict__ s,
                                               const float* __restrict__ P,
                                               float* __restrict__ w,
                                               float* __restrict__ agg) {
  const int fb = blockIdx.x, b = blockIdx.y, t = threadIdx.x;
  const int wave = t >> 6, lane = t & 63;
  __shared__ float lred[4];

  float e[4];
  float sum = 0.f;
  #pragma unroll
  for (int i = 0; i < 4; ++i) {
    e[i] = expf(s[(size_t)b * Nn + t + i * 256]);
    sum += e[i];
  }
  #pragma unroll
  for (int off = 32; off > 0; off >>= 1) sum += __shfl_xor(sum, off);
  if (lane == 0) lred[wave] = sum;
  __syncthreads();
  sum = lred[0] + lred[1] + lred[2] + lred[3];
  const float inv = 1.0f / sum;

  // this block's quarter of w: positions [fb*256, fb*256+256)
  w[(size_t)b * Nn + fb * 256 + t] = e[fb] * inv;

  // this block's 128-column slice of agg: d in [fb*128, fb*128+128)
  if (t < 128) {
    const int d = fb * 128 + t;
    float g = 0.f;
    #pragma unroll 8
    for (int chh = 0; chh < SCH; ++chh)
      g += P[(size_t)(b * SCH + chh) * Dd + d];
    agg[(size_t)b * Dd + d] = g * inv;
  }
}

}  // namespace

extern "C" void kernel_launch(void* const* d_in, const int* in_sizes, int n_in,
                              void* d_out, int out_size, void* d_ws, size_t ws_size,
                              hipStream_t stream) {
  const float* x  = (const float*)d_in[0];
  const float* Wq = (const float*)d_in[1];
  const float* Wk = (const float*)d_in[3];
  const float* bk = (const float*)d_in[4];

  float* out = (float*)d_out;
  float* agg = out;                       // [B][D]
  float* w   = out + (size_t)Bsz * Dd;    // [B][N]

  // workspace (floats): part | upart | s | P   (~5.5 MiB)
  float* part  = (float*)d_ws;                          // B*PPB*D = 524288
  float* upart = part + (size_t)Bsz * PPB * Dd;         // B*GCH*D = 262144
  float* s     = upart + (size_t)Bsz * GCH * Dd;        // B*N     =  65536
  float* P     = s + (size_t)Bsz * Nn;                  // B*SCH*D = 524288

  k_colsum<<<dim3(NCH, Bsz), 256, 0, stream>>>(x, part);
  k_prep2 <<<dim3(GCH, Bsz), 256, 0, stream>>>(part, Wq, Wk, bk, upart);
  k_fused <<<dim3(SCH, Bsz), 256, 0, stream>>>(x, upart, s, P);
  k_final <<<dim3(FB, Bsz), 256, 0, stream>>>(s, P, w, agg);
}